// Round 1
// baseline (2793.422 us; speedup 1.0000x reference)
//
#include <hip/hip_runtime.h>
#include <math.h>

// ---------------------------------------------------------------------------
// Problem: CausalSelfAttention  B=4 T=2048 C=1024 H=16 D=64, fp32 in/out.
//   qkv = x @ w_attn            [8192,1024]@[1024,3072]
//   attn (causal, per head)     D=64
//   out = y @ w_proj            [8192,1024]@[1024,1024]
// Round 0: correctness-first fp32. qkv lives in d_ws (96 MB); attention
// output is written in-place into the q-slot of qkv (cols 0..1023).
// ---------------------------------------------------------------------------

// C[M,N] = A[M,K] @ B[K,N], row-major with explicit leading dims (elements).
// 64x64 tile, BK=16, 256 threads, 4x4 per thread. M,N,K multiples of 64/16.
__global__ __launch_bounds__(256)
void sgemm64(const float* __restrict__ A, int lda,
             const float* __restrict__ B, int ldb,
             float* __restrict__ C, int ldc,
             int M, int N, int K)
{
    __shared__ float As[16][65];   // [k][m], +1 pad
    __shared__ float Bs[16][65];   // [k][n], +1 pad
    const int tid = threadIdx.x;
    const int row0 = blockIdx.y * 64, col0 = blockIdx.x * 64;
    const int tx = tid & 15, ty = tid >> 4;

    const int ar = tid >> 4;   // row-within-pass for A loads (16 rows/pass)
    const int ak = tid & 15;   // k for A loads
    const int bk = tid >> 6;   // k-within-pass for B loads (4 k/pass)
    const int bn = tid & 63;   // n for B loads

    float acc[4][4] = {};

    for (int k0 = 0; k0 < K; k0 += 16) {
#pragma unroll
        for (int p = 0; p < 4; ++p) {
            int r = p * 16 + ar;
            As[ak][r] = A[(size_t)(row0 + r) * lda + (k0 + ak)];
            int kk = p * 4 + bk;
            Bs[kk][bn] = B[(size_t)(k0 + kk) * ldb + (col0 + bn)];
        }
        __syncthreads();
#pragma unroll
        for (int kk = 0; kk < 16; ++kk) {
            float a[4], b[4];
#pragma unroll
            for (int i = 0; i < 4; ++i) a[i] = As[kk][ty * 4 + i];
#pragma unroll
            for (int j = 0; j < 4; ++j) b[j] = Bs[kk][tx * 4 + j];
#pragma unroll
            for (int i = 0; i < 4; ++i)
#pragma unroll
                for (int j = 0; j < 4; ++j)
                    acc[i][j] += a[i] * b[j];
        }
        __syncthreads();
    }
#pragma unroll
    for (int i = 0; i < 4; ++i)
#pragma unroll
        for (int j = 0; j < 4; ++j)
            C[(size_t)(row0 + ty * 4 + i) * ldc + (col0 + tx * 4 + j)] = acc[i][j];
}

// ---------------------------------------------------------------------------
// Flash-style causal attention.
// Grid: (T/64, H, B). Block: 256 threads = 4 sub-groups (tg) x 64 rows (r).
// Thread (tg, r) owns query row r of the tile and output cols [tg*16, tg*16+16).
// For scores, tg owns key cols j in [tg*16, tg*16+16); softmax stats are
// reduced across the 4 tgs via LDS; P is exchanged via LDS for the PV matmul.
// Writes y in-place into the q region of qkv (cols h*64..h*64+63 of block 0).
// ---------------------------------------------------------------------------
#define LDP 68   // LDS row stride: keeps float4 alignment (68%4==0)

__global__ __launch_bounds__(256)
void attn_kernel(float* __restrict__ qkv, int T)
{
    const int qb = blockIdx.x;
    const int h  = blockIdx.y;
    const int b  = blockIdx.z;
    const int tid = threadIdx.x;
    const int r  = tid & 63;   // query row within tile
    const int tg = tid >> 6;   // 0..3

    __shared__ float Ks[64][LDP];
    __shared__ float Vs[64][LDP];
    __shared__ float Ps[64][LDP];
    __shared__ float red[64][8];

    const size_t rowbase = (size_t)(b * T) * 3072;
    const float scale = 0.125f;   // 1/sqrt(64)

    // Q row -> registers (16 float4 = 64 floats). Redundant across tgs; cached.
    float qreg[64];
    {
        const float4* qp = (const float4*)(qkv + rowbase +
                            (size_t)(qb * 64 + r) * 3072 + h * 64);
#pragma unroll
        for (int d4 = 0; d4 < 16; ++d4) {
            float4 q4 = qp[d4];
            qreg[d4 * 4 + 0] = q4.x; qreg[d4 * 4 + 1] = q4.y;
            qreg[d4 * 4 + 2] = q4.z; qreg[d4 * 4 + 3] = q4.w;
        }
    }

    float m = -1e30f, l = 0.f;
    float acc[16];
#pragma unroll
    for (int i = 0; i < 16; ++i) acc[i] = 0.f;

    for (int jb = 0; jb <= qb; ++jb) {
        // ---- load K,V tile (64x64 each) cooperatively, float4, coalesced ----
#pragma unroll
        for (int p = 0; p < 4; ++p) {
            int idx = p * 256 + tid;
            int rr = idx >> 4;
            int cc = (idx & 15) * 4;
            const float* kp = qkv + rowbase + (size_t)(jb * 64 + rr) * 3072
                              + 1024 + h * 64 + cc;
            *(float4*)&Ks[rr][cc] = *(const float4*)kp;
            *(float4*)&Vs[rr][cc] = *(const float4*)(kp + 1024);
        }
        __syncthreads();

        // ---- scores for this tg's 16 key columns ----
        float sv[16];
        float smax = -1e30f;
#pragma unroll
        for (int jj = 0; jj < 16; ++jj) {
            int j = tg * 16 + jj;
            const float4* kr = (const float4*)&Ks[j][0];   // wave-broadcast reads
            float dot = 0.f;
#pragma unroll
            for (int d4 = 0; d4 < 16; ++d4) {
                float4 k4 = kr[d4];
                dot += qreg[d4 * 4 + 0] * k4.x + qreg[d4 * 4 + 1] * k4.y
                     + qreg[d4 * 4 + 2] * k4.z + qreg[d4 * 4 + 3] * k4.w;
            }
            dot *= scale;
            if (jb == qb && j > r) dot = -1e30f;   // causal mask (finite: no NaN)
            sv[jj] = dot;
            smax = fmaxf(smax, dot);
        }
        red[r][tg] = smax;
        __syncthreads();

        float mnew = fmaxf(fmaxf(red[r][0], red[r][1]),
                           fmaxf(red[r][2], red[r][3]));
        mnew = fmaxf(mnew, m);

        float lsum = 0.f;
#pragma unroll
        for (int jj = 0; jj < 16; ++jj) {
            float p = __expf(sv[jj] - mnew);
            Ps[r][tg * 16 + jj] = p;
            lsum += p;
        }
        red[r][4 + tg] = lsum;
        __syncthreads();

        float alpha = __expf(m - mnew);
        l = l * alpha + (red[r][4] + red[r][5] + red[r][6] + red[r][7]);
        m = mnew;
#pragma unroll
        for (int i = 0; i < 16; ++i) acc[i] *= alpha;

        // ---- O += P @ V for this tg's 16 output cols ----
#pragma unroll 4
        for (int j = 0; j < 64; ++j) {
            float p = Ps[r][j];
            const float4* vr = (const float4*)&Vs[j][tg * 16];  // broadcast
            float4 v0 = vr[0], v1 = vr[1], v2 = vr[2], v3 = vr[3];
            acc[0]  += p * v0.x; acc[1]  += p * v0.y;
            acc[2]  += p * v0.z; acc[3]  += p * v0.w;
            acc[4]  += p * v1.x; acc[5]  += p * v1.y;
            acc[6]  += p * v1.z; acc[7]  += p * v1.w;
            acc[8]  += p * v2.x; acc[9]  += p * v2.y;
            acc[10] += p * v2.z; acc[11] += p * v2.w;
            acc[12] += p * v3.x; acc[13] += p * v3.y;
            acc[14] += p * v3.z; acc[15] += p * v3.w;
        }
        __syncthreads();   // before next tile overwrites Ks/Vs/Ps
    }

    // ---- write y into q slot (cols 0..1023) of qkv ----
    const float inv = 1.f / l;
    float* yp = qkv + rowbase + (size_t)(qb * 64 + r) * 3072 + h * 64 + tg * 16;
#pragma unroll
    for (int i = 0; i < 16; i += 4) {
        float4 o;
        o.x = acc[i + 0] * inv; o.y = acc[i + 1] * inv;
        o.z = acc[i + 2] * inv; o.w = acc[i + 3] * inv;
        *(float4*)(yp + i) = o;
    }
}

extern "C" void kernel_launch(void* const* d_in, const int* in_sizes, int n_in,
                              void* d_out, int out_size, void* d_ws, size_t ws_size,
                              hipStream_t stream)
{
    const float* x      = (const float*)d_in[0];   // [4,2048,1024]
    const float* w_attn = (const float*)d_in[1];   // [1024,3072]
    const float* w_proj = (const float*)d_in[2];   // [1024,1024]
    float* out = (float*)d_out;                    // [4,2048,1024]
    float* qkv = (float*)d_ws;                     // [8192,3072] fp32 = 96 MB

    const int Bb = 4, T = 2048, C = 1024;
    const int M = Bb * T;                          // 8192

    // qkv = x @ w_attn
    hipLaunchKernelGGL(sgemm64, dim3(3 * C / 64, M / 64), dim3(256), 0, stream,
                       x, C, w_attn, 3 * C, qkv, 3 * C, M, 3 * C, C);

    // causal attention; y written into q slot of qkv
    hipLaunchKernelGGL(attn_kernel, dim3(T / 64, 16, Bb), dim3(256), 0, stream,
                       qkv, T);

    // out = y @ w_proj
    hipLaunchKernelGGL(sgemm64, dim3(C / 64, M / 64), dim3(256), 0, stream,
                       qkv, 3 * C, w_proj, C, out, C, M, C, C);
}

// Round 3
// 437.900 us; speedup vs baseline: 6.3791x; 6.3791x over previous
//
#include <hip/hip_runtime.h>
#include <math.h>

// ---------------------------------------------------------------------------
// CausalSelfAttention  B=4 T=2048 C=1024 H=16 D=64, fp32 in/out.
// Round 2b: full bf16 MFMA pipeline (fixes macro/braced-init compile error).
//   prologue: cast x -> bf16; transpose+cast w_attn, w_proj -> [N][K] bf16
//   GEMM1 (MFMA 128x128, BK=32, global_load_lds): qkv scattered to
//          Qh[b,h,t,d], Kh[b,h,t,d], Vt[b,h,d,t]  (V pre-transposed!)
//   attn:  flash MFMA, 64 q-rows/block, online softmax via shfl, P via LDS
//   GEMM2: y @ w_projT -> fp32 out
// ---------------------------------------------------------------------------

typedef unsigned short ushort_t;
typedef __attribute__((ext_vector_type(8))) short bf16x8;   // 8 bf16 (4 VGPRs)
typedef __attribute__((ext_vector_type(4))) float f32x4;

#define MFMA16(a, b, c) __builtin_amdgcn_mfma_f32_16x16x32_bf16((a), (b), (c), 0, 0, 0)

#define CP_ASYNC16(lds, gp)                                                        \
    __builtin_amdgcn_global_load_lds(                                              \
        (const __attribute__((address_space(1))) void*)(gp),                       \
        (__attribute__((address_space(3))) void*)(lds), 16, 0, 0)

__device__ __forceinline__ ushort_t bf16r(float x) {
    unsigned int u = __float_as_uint(x);
    u += 0x7FFFu + ((u >> 16) & 1u);      // round-to-nearest-even
    return (ushort_t)(u >> 16);
}

// ---------------- prologue kernels ----------------

__global__ __launch_bounds__(256) void cast_f32_bf16(const float4* __restrict__ src,
                                                     ushort4* __restrict__ dst) {
    int i = blockIdx.x * 256 + threadIdx.x;
    float4 v = src[i];
    ushort4 o;
    o.x = bf16r(v.x); o.y = bf16r(v.y); o.z = bf16r(v.z); o.w = bf16r(v.w);
    dst[i] = o;
}

// src fp32 [R][Cc] -> dst bf16 [Cc][R]
__global__ __launch_bounds__(256) void transpose_cast(const float* __restrict__ src,
                                                      ushort_t* __restrict__ dst,
                                                      int R, int Cc) {
    __shared__ float tile[32][33];
    const int tx = threadIdx.x, ty = threadIdx.y;       // block (32,8)
    const int c0 = blockIdx.x * 32, r0 = blockIdx.y * 32;
#pragma unroll
    for (int i = 0; i < 4; ++i)
        tile[ty + i * 8][tx] = src[(size_t)(r0 + ty + i * 8) * Cc + c0 + tx];
    __syncthreads();
#pragma unroll
    for (int i = 0; i < 4; ++i)
        dst[(size_t)(c0 + ty + i * 8) * R + r0 + tx] = bf16r(tile[tx][ty + i * 8]);
}

// ---------------- MFMA GEMM: C[M,N] = A[M,K] @ Bt[N,K]^T ----------------
// 128x128 tile, BK=32, 256 threads (4 waves, 2x2), 4x4 16x16 tiles per wave.
// mode 0: scatter bf16 into Qh/Kh/Vt (GEMM1, N=3072)
// mode 1: plain fp32 store to Cout with ldc=1024 (GEMM2)
__global__ __launch_bounds__(256)
void gemm_bf16(const ushort_t* __restrict__ A, const ushort_t* __restrict__ Bt,
               int K, int mode,
               ushort_t* __restrict__ Qh, ushort_t* __restrict__ Kh,
               ushort_t* __restrict__ Vt, float* __restrict__ Cout) {
    __shared__ ushort_t As[128 * 32];
    __shared__ ushort_t Bs[128 * 32];
    const int tid = threadIdx.x;
    const int l = tid & 63, w = tid >> 6;
    const int lm = l & 15, lq = l >> 4;
    const int wm = w >> 1, wn = w & 1;
    const int row0 = blockIdx.y * 128, col0 = blockIdx.x * 128;
    const f32x4 zero4 = {0.f, 0.f, 0.f, 0.f};

    f32x4 acc[4][4];
#pragma unroll
    for (int i = 0; i < 4; ++i)
#pragma unroll
        for (int j = 0; j < 4; ++j) acc[i][j] = zero4;

    // staging pointers: thread idx covers [row=idx>>2][8-elem chunk idx&3]
    const ushort_t* ga0 = A + (size_t)(row0 + (tid >> 2)) * K + (tid & 3) * 8;
    const ushort_t* ga1 = ga0 + (size_t)64 * K;
    const ushort_t* gb0 = Bt + (size_t)(col0 + (tid >> 2)) * K + (tid & 3) * 8;
    const ushort_t* gb1 = gb0 + (size_t)64 * K;
    ushort_t* la0 = As + tid * 8;
    ushort_t* la1 = As + (tid + 256) * 8;
    ushort_t* lb0 = Bs + tid * 8;
    ushort_t* lb1 = Bs + (tid + 256) * 8;

    const int aoffb = (wm * 64 + lm) * 32 + lq * 8;
    const int boffb = (wn * 64 + lm) * 32 + lq * 8;

    for (int k0 = 0; k0 < K; k0 += 32) {
        CP_ASYNC16(la0, ga0); CP_ASYNC16(la1, ga1);
        CP_ASYNC16(lb0, gb0); CP_ASYNC16(lb1, gb1);
        ga0 += 32; ga1 += 32; gb0 += 32; gb1 += 32;
        __syncthreads();                       // drains DMA (vmcnt) + all waves
        bf16x8 af[4], bfr[4];
#pragma unroll
        for (int i = 0; i < 4; ++i)
            af[i] = *(const bf16x8*)(As + aoffb + i * (16 * 32));
#pragma unroll
        for (int j = 0; j < 4; ++j)
            bfr[j] = *(const bf16x8*)(Bs + boffb + j * (16 * 32));
#pragma unroll
        for (int i = 0; i < 4; ++i)
#pragma unroll
            for (int j = 0; j < 4; ++j)
                acc[i][j] = MFMA16(af[i], bfr[j], acc[i][j]);
        __syncthreads();                       // protect LDS before next stage
    }

    // epilogue: C/D layout col=lane&15, row=(lane>>4)*4+reg
#pragma unroll
    for (int i = 0; i < 4; ++i) {
#pragma unroll
        for (int j = 0; j < 4; ++j) {
#pragma unroll
            for (int reg = 0; reg < 4; ++reg) {
                const int rr = row0 + wm * 64 + i * 16 + lq * 4 + reg;
                const int cc = col0 + wn * 64 + j * 16 + lm;
                const float v = acc[i][j][reg];
                if (mode == 1) {
                    Cout[(size_t)rr * 1024 + cc] = v;
                } else {
                    const int b = rr >> 11, t = rr & 2047;
                    if (cc < 1024) {
                        const int h = cc >> 6, d = cc & 63;
                        Qh[((size_t)(b * 16 + h) * 2048 + t) * 64 + d] = bf16r(v);
                    } else if (cc < 2048) {
                        const int c2 = cc - 1024, h = c2 >> 6, d = c2 & 63;
                        Kh[((size_t)(b * 16 + h) * 2048 + t) * 64 + d] = bf16r(v);
                    } else {
                        const int c2 = cc - 2048, h = c2 >> 6, d = c2 & 63;
                        Vt[((size_t)(b * 16 + h) * 64 + d) * 2048 + t] = bf16r(v);
                    }
                }
            }
        }
    }
}

// ---------------- flash attention, MFMA ----------------
// grid (T/64, H, B), 256 threads. Wave w owns q rows [w*16, w*16+16).
// Ks: [2 d-chunks][64 keys][32 d]   Vs: [2 key-chunks][64 d][32 keys]
// Ps: per wave [2 key-chunks][16 q][40(pad)] bf16
__global__ __launch_bounds__(256)
void attn_mfma(const ushort_t* __restrict__ Qh, const ushort_t* __restrict__ Kh,
               const ushort_t* __restrict__ Vt, ushort_t* __restrict__ Y) {
    __shared__ ushort_t Ks[2 * 64 * 32];
    __shared__ ushort_t Vs[2 * 64 * 32];
    __shared__ ushort_t Ps[4][2 * 16 * 40];
    const int tid = threadIdx.x, l = tid & 63, w = tid >> 6;
    const int lm = l & 15, lq = l >> 4;
    const int qb = (int)gridDim.x - 1 - (int)blockIdx.x;   // long blocks first
    const int h = blockIdx.y, b = blockIdx.z;
    const int bh = b * 16 + h;
    const int t0 = qb * 64;
    const f32x4 zero4 = {0.f, 0.f, 0.f, 0.f};

    // Q fragments (A-operand): rows t0 + w*16 + lm, k-chunks d 0..31 / 32..63
    const ushort_t* qp = Qh + ((size_t)bh * 2048 + t0 + w * 16 + lm) * 64 + lq * 8;
    const bf16x8 qf0 = *(const bf16x8*)(qp);
    const bf16x8 qf1 = *(const bf16x8*)(qp + 32);

    f32x4 O[4];
#pragma unroll
    for (int i = 0; i < 4; ++i) O[i] = zero4;
    float m_run[4] = {-1e30f, -1e30f, -1e30f, -1e30f};
    float l_run[4] = {0.f, 0.f, 0.f, 0.f};

    // staging: thread covers row=tid>>2, chunk=(tid&3)*8
    const int srow = tid >> 2, scol = (tid & 3) * 8;
    const ushort_t* gk0 = Kh + ((size_t)bh * 2048 + srow) * 64 + scol;      // d 0..31
    const ushort_t* gk1 = gk0 + 32;                                          // d 32..63
    const ushort_t* gv0 = Vt + ((size_t)bh * 64 + srow) * 2048 + scol;       // keys 0..31
    const ushort_t* gv1 = gv0 + 32;                                          // keys 32..63
    ushort_t* lk0 = Ks + tid * 8;  ushort_t* lk1 = Ks + (tid + 256) * 8;
    ushort_t* lv0 = Vs + tid * 8;  ushort_t* lv1 = Vs + (tid + 256) * 8;
    ushort_t* PsW = Ps[w];

    for (int jb = 0; jb <= qb; ++jb) {
        __syncthreads();                       // prev-iter LDS reads done
        const size_t kof = (size_t)jb * 64;
        CP_ASYNC16(lk0, gk0 + kof * 64);
        CP_ASYNC16(lk1, gk1 + kof * 64);
        CP_ASYNC16(lv0, gv0 + kof);
        CP_ASYNC16(lv1, gv1 + kof);
        __syncthreads();                       // DMA visible

        // S = Q K^T  (4 key-tiles of 16, D split in two 32-chunks)
        f32x4 sf[4];
#pragma unroll
        for (int n = 0; n < 4; ++n) {
            const bf16x8 kf0 = *(const bf16x8*)(Ks + (n * 16 + lm) * 32 + lq * 8);
            const bf16x8 kf1 = *(const bf16x8*)(Ks + 2048 + (n * 16 + lm) * 32 + lq * 8);
            f32x4 s_acc = zero4;
            s_acc = MFMA16(qf0, kf0, s_acc);
            s_acc = MFMA16(qf1, kf1, s_acc);
            sf[n] = s_acc;
        }

        const bool diag = (jb == qb);
        float p[4][4];                          // [key-tile][reg]
#pragma unroll
        for (int reg = 0; reg < 4; ++reg) {
            const int qloc = w * 16 + lq * 4 + reg;   // q row within 64-tile
            float s[4];
#pragma unroll
            for (int n = 0; n < 4; ++n) {
                float sv = sf[n][reg] * 0.125f;
                if (diag && (n * 16 + lm) > qloc) sv = -1e30f;
                s[n] = sv;
            }
            float rmax = fmaxf(fmaxf(s[0], s[1]), fmaxf(s[2], s[3]));
            rmax = fmaxf(rmax, __shfl_xor(rmax, 1));
            rmax = fmaxf(rmax, __shfl_xor(rmax, 2));
            rmax = fmaxf(rmax, __shfl_xor(rmax, 4));
            rmax = fmaxf(rmax, __shfl_xor(rmax, 8));
            const float mnew = fmaxf(m_run[reg], rmax);
            const float al = __expf(m_run[reg] - mnew);
            m_run[reg] = mnew;
            float ps = 0.f;
#pragma unroll
            for (int n = 0; n < 4; ++n) { p[n][reg] = __expf(s[n] - mnew); ps += p[n][reg]; }
            ps += __shfl_xor(ps, 1);
            ps += __shfl_xor(ps, 2);
            ps += __shfl_xor(ps, 4);
            ps += __shfl_xor(ps, 8);
            l_run[reg] = l_run[reg] * al + ps;
#pragma unroll
            for (int dn = 0; dn < 4; ++dn) O[dn][reg] *= al;
        }

        // P -> LDS (C-layout -> A-operand layout), bf16
#pragma unroll
        for (int n = 0; n < 4; ++n) {
            const int ch = n >> 1, nn = n & 1;
#pragma unroll
            for (int reg = 0; reg < 4; ++reg)
                PsW[(ch * 16 + lq * 4 + reg) * 40 + nn * 16 + lm] = bf16r(p[n][reg]);
        }

        // O += P V  (keys split in two 32-chunks)
        const bf16x8 pf0 = *(const bf16x8*)(PsW + lm * 40 + lq * 8);
        const bf16x8 pf1 = *(const bf16x8*)(PsW + (16 + lm) * 40 + lq * 8);
#pragma unroll
        for (int dn = 0; dn < 4; ++dn) {
            const bf16x8 vf0 = *(const bf16x8*)(Vs + (dn * 16 + lm) * 32 + lq * 8);
            const bf16x8 vf1 = *(const bf16x8*)(Vs + 2048 + (dn * 16 + lm) * 32 + lq * 8);
            O[dn] = MFMA16(pf0, vf0, O[dn]);
            O[dn] = MFMA16(pf1, vf1, O[dn]);
        }
    }

    // epilogue: y[b*2048+t][h*64+d] bf16
#pragma unroll
    for (int reg = 0; reg < 4; ++reg) {
        const float inv = 1.f / l_run[reg];
        const size_t row = (size_t)b * 2048 + t0 + w * 16 + lq * 4 + reg;
#pragma unroll
        for (int dn = 0; dn < 4; ++dn)
            Y[row * 1024 + h * 64 + dn * 16 + lm] = bf16r(O[dn][reg] * inv);
    }
}

// ---------------- launch ----------------

extern "C" void kernel_launch(void* const* d_in, const int* in_sizes, int n_in,
                              void* d_out, int out_size, void* d_ws, size_t ws_size,
                              hipStream_t stream) {
    const float* x      = (const float*)d_in[0];   // [8192,1024]
    const float* w_attn = (const float*)d_in[1];   // [1024,3072]
    const float* w_proj = (const float*)d_in[2];   // [1024,1024]
    float* out = (float*)d_out;

    char* ws = (char*)d_ws;
    ushort_t* xb   = (ushort_t*)(ws);                       // 16 MB  [8192][1024]
    ushort_t* watT = (ushort_t*)(ws + 16777216);            // 6 MB   [3072][1024]
    ushort_t* wpjT = (ushort_t*)(ws + 23068672);            // 2 MB   [1024][1024]
    ushort_t* Qh   = (ushort_t*)(ws + 25165824);            // 16 MB  [b,h,t,d]
    ushort_t* Kh   = (ushort_t*)(ws + 41943040);            // 16 MB  [b,h,t,d]
    ushort_t* Vt   = (ushort_t*)(ws + 58720256);            // 16 MB  [b,h,d,t]
    ushort_t* Y    = (ushort_t*)(ws + 75497472);            // 16 MB  [8192][1024]

    // prologue
    hipLaunchKernelGGL(cast_f32_bf16, dim3(8192), dim3(256), 0, stream,
                       (const float4*)x, (ushort4*)xb);
    hipLaunchKernelGGL(transpose_cast, dim3(96, 32), dim3(32, 8), 0, stream,
                       w_attn, watT, 1024, 3072);
    hipLaunchKernelGGL(transpose_cast, dim3(32, 32), dim3(32, 8), 0, stream,
                       w_proj, wpjT, 1024, 1024);

    // qkv = x @ w_attn, scattered into Qh/Kh/Vt
    hipLaunchKernelGGL(gemm_bf16, dim3(24, 64), dim3(256), 0, stream,
                       xb, watT, 1024, 0, Qh, Kh, Vt, (float*)nullptr);

    // flash attention
    hipLaunchKernelGGL(attn_mfma, dim3(32, 16, 4), dim3(256), 0, stream,
                       Qh, Kh, Vt, Y);

    // out = y @ w_proj
    hipLaunchKernelGGL(gemm_bf16, dim3(8, 64), dim3(256), 0, stream,
                       Y, wpjT, 1024, 1, (ushort_t*)nullptr, (ushort_t*)nullptr,
                       (ushort_t*)nullptr, out);
}